// Round 9
// baseline (387.854 us; speedup 1.0000x reference)
//
#include <hip/hip_runtime.h>

#define WINDOW   512
#define STEPSZ   256
#define NFRAMES  127
#define NSAMP    32768
#define NBATCH   512
#define NFREQ    256
#define BM       128
#define SAMP_TILE 33024          // 129 * 256 samples per batch tile
#define NPS      129

typedef __attribute__((ext_vector_type(8))) short short8;   // 8 x bf16
typedef __attribute__((ext_vector_type(4))) float f32x4;
typedef __attribute__((ext_vector_type(4))) float f4;

// Verified pattern (G4): spread row-bits (byte bits 9-11) into 16B-slot bits.
#define SWZ(byt) ((byt) ^ ((((byt) >> 9) & 7) << 4))

static __device__ __forceinline__ short f2bf(float x) {
    union { float f; unsigned u; } v; v.f = x;
    unsigned r = (v.u + 0x7fffu + ((v.u >> 16) & 1u)) >> 16;
    return (short)r;
}

// ---- kernel 1: normalize basis -> bf16 fragment-major layout in d_ws ----
// frag[(ntg*16 + kk)*64 + (kgrp*16 + rlane)][8] holds
// B[n = ntg*16 + rlane][k = kk*32 + kgrp*8 + j]; real ntg 0..15, imag 16..31.
__global__ __launch_bounds__(256) void prep_kernel(const float* __restrict__ br,
                                                   const float* __restrict__ bi,
                                                   short* __restrict__ Bf) {
    const int lane = threadIdx.x & 63;
    const int wid  = threadIdx.x >> 6;
    const int k    = blockIdx.x * 4 + wid;          // freq 0..255
    const float* pr = br + (size_t)k * WINDOW + lane * 8;
    const float* pi = bi + (size_t)k * WINDOW + lane * 8;
    f4 r0 = *(const f4*)pr;
    f4 r1 = *(const f4*)(pr + 4);
    f4 i0 = *(const f4*)pi;
    f4 i1 = *(const f4*)(pi + 4);
    float ss = 0.f;
#pragma unroll
    for (int j = 0; j < 4; ++j)
        ss += r0[j]*r0[j] + r1[j]*r1[j] + i0[j]*i0[j] + i1[j]*i1[j];
#pragma unroll
    for (int d = 1; d < 64; d <<= 1) ss += __shfl_xor(ss, d, 64);
    const float inv = 1.0f / (sqrtf(ss) + 1e-8f);
    short8 hr, hi;
#pragma unroll
    for (int j = 0; j < 4; ++j) {
        hr[j]     = f2bf(r0[j] * inv);
        hr[j + 4] = f2bf(r1[j] * inv);
        hi[j]     = f2bf(i0[j] * inv);
        hi[j + 4] = f2bf(i1[j] * inv);
    }
    const int kk = lane >> 2, kgrp = lane & 3;
    const int rl  = k & 15;
    const int ntR = k >> 4;
    const int ntI = 16 + (k >> 4);
    *(short8*)(Bf + ((size_t)(ntR * 16 + kk) * 64 + kgrp * 16 + rl) * 8) = hr;
    *(short8*)(Bf + ((size_t)(ntI * 16 + kk) * 64 + kgrp * 16 + rl) * 8) = hi;
}

// ---- kernel 2: fused norms + bf16 MFMA GEMM --------------------------------
// grid = 512 (one block per batch); 1024 thr (16 waves).
// Block = 128 frames x 512 cols (WHOLE batch): staging once per batch, B read
// once per batch (256 MB L2 total). Wave = 8m x 2n (R7's verified write
// pattern). 2 blocks/CU resident (LDS 67 KB, ~134 unified regs).
__global__ __launch_bounds__(1024, 8) void mel_kernel(const float* __restrict__ audio,
                                                      const short* __restrict__ Bf,
                                                      float* __restrict__ out) {
    __shared__ short smp[SAMP_TILE];   // 66048 B, swizzled bf16 samples
    __shared__ float ps[NPS];
    __shared__ float invn[BM];

    const int tid  = threadIdx.x;
    const int lane = tid & 63;
    const int wid  = tid >> 6;          // 0..15

    const int b = blockIdx.x;

    float* out_norms = out;
    float* out_real  = out + 65024;
    float* out_imag  = out + 65024 + 16646144;

    const float* abase = audio + (size_t)b * NSAMP;
    const int smax = NSAMP - 8;

    const int rlane = lane & 15;
    const int kgrp  = lane >> 4;
    const int ntg0  = wid * 2;          // 2 n-tiles per wave

    const short* bp0 = Bf + ((size_t)(ntg0 + 0) * 16 * 64 + lane) * 8;
    const short* bp1 = Bf + ((size_t)(ntg0 + 1) * 16 * 64 + lane) * 8;

    // ---- depth-3 B prefetch (independent of LDS phase) ----
    short8 bb[3][2];
#pragma unroll
    for (int d = 0; d < 3; ++d) {
        bb[d][0] = *(const short8*)(bp0 + (size_t)d * 512);
        bb[d][1] = *(const short8*)(bp1 + (size_t)d * 512);
    }

    // ---- Phase 1: stream 8 samples/thread: f32 -> ss partial + bf16 LDS ----
#pragma unroll
    for (int it = 0; it < 5; ++it) {
        const int sl = it * 8192 + tid * 8;
        float ss = 0.f;
        if (sl < SAMP_TILE) {
            const int slc = sl < smax ? sl : smax;
            f4 v0 = *(const f4*)(abase + slc);
            f4 v1 = *(const f4*)(abase + slc + 4);
            short8 h;
#pragma unroll
            for (int q = 0; q < 4; ++q) {
                ss += v0[q]*v0[q] + v1[q]*v1[q];
                h[q]     = f2bf(v0[q]);
                h[q + 4] = f2bf(v1[q]);
            }
            const int byt = sl * 2;
            *(short8*)((char*)smp + SWZ(byt)) = h;
        }
        ss += __shfl_xor(ss, 1, 64);
        ss += __shfl_xor(ss, 2, 64);
        ss += __shfl_xor(ss, 4, 64);
        ss += __shfl_xor(ss, 8, 64);
        ss += __shfl_xor(ss, 16, 64);
        const int chunk = (it * 8192 + tid * 8) >> 8;
        if ((tid & 31) == 0 && chunk < NPS) ps[chunk] = ss;
    }
    __syncthreads();

    // ---- norms: frame f covers chunks f, f+1 ----
    if (tid < BM) {
        const float nrm = sqrtf(ps[tid] + ps[tid + 1]);
        if (tid < NFRAMES) out_norms[b * NFRAMES + tid] = nrm;
        invn[tid] = 1.0f / (nrm + 1e-8f);
    }

    // ---- Phase 2: K-loop ----
    const int rb = rlane * 512 + kgrp * 16;
    const int X0 = (rlane & 7) << 4;
    const int X1 = ((rlane + 1) & 7) << 4;
    const char* sb = (const char*)smp;

    f32x4 acc[8][2];
#pragma unroll
    for (int mt = 0; mt < 8; ++mt) { acc[mt][0] = (f32x4)0.f; acc[mt][1] = (f32x4)0.f; }

#pragma unroll
    for (int kk = 0; kk < 16; ++kk) {
        const int X  = (kk < 8) ? X0 : X1;
        const int kb = kk * 64;
        short8 a[8];
#pragma unroll
        for (int mt = 0; mt < 8; ++mt)
            a[mt] = *(const short8*)(sb + ((rb + mt * 8192 + kb) ^ X));
        const int cur = kk % 3;
        short8 cb0 = bb[cur][0];
        short8 cb1 = bb[cur][1];
        if (kk < 13) {
            bb[cur][0] = *(const short8*)(bp0 + (size_t)(kk + 3) * 512);
            bb[cur][1] = *(const short8*)(bp1 + (size_t)(kk + 3) * 512);
        }
#pragma unroll
        for (int mt = 0; mt < 8; ++mt) {
            acc[mt][0] = __builtin_amdgcn_mfma_f32_16x16x32_bf16(a[mt], cb0, acc[mt][0], 0, 0, 0);
            acc[mt][1] = __builtin_amdgcn_mfma_f32_16x16x32_bf16(a[mt], cb1, acc[mt][1], 0, 0, 0);
        }
    }
    __syncthreads();   // invn visible to all epilogue readers

    // ---- Epilogue: scale by 1/norm, store ----
#pragma unroll
    for (int mt = 0; mt < 8; ++mt) {
        const int rbase = mt * 16 + kgrp * 4;
#pragma unroll
        for (int nt = 0; nt < 2; ++nt) {
            const int n = (ntg0 + nt) * 16 + rlane;
            float* dst = (n < NFREQ) ? out_real : out_imag;
            const int kcol = n & (NFREQ - 1);
#pragma unroll
            for (int j = 0; j < 4; ++j) {
                const int fr = rbase + j;
                if (fr < NFRAMES)
                    dst[((size_t)b * NFRAMES + fr) * NFREQ + kcol] = acc[mt][nt][j] * invn[fr];
            }
        }
    }
}

extern "C" void kernel_launch(void* const* d_in, const int* in_sizes, int n_in,
                              void* d_out, int out_size, void* d_ws, size_t ws_size,
                              hipStream_t stream) {
    const float* audio = (const float*)d_in[0];
    const float* br    = (const float*)d_in[1];
    const float* bi    = (const float*)d_in[2];
    float* out = (float*)d_out;
    short* Bf  = (short*)d_ws;               // 512x512 bf16 = 512 KiB

    prep_kernel<<<64, 256, 0, stream>>>(br, bi, Bf);
    mel_kernel<<<NBATCH, 1024, 0, stream>>>(audio, Bf, out);
}

// Round 10
// 64.245 us; speedup vs baseline: 6.0371x; 6.0371x over previous
//
#include <hip/hip_runtime.h>

#define WINDOW   512
#define STEPSZ   256
#define NFRAMES  127
#define NSAMP    32768
#define NBATCH   512
#define NFREQ    256
#define BM       128
#define SAMP_TILE 33024          // 129 * 256 samples per batch tile
#define NPS      129

typedef __attribute__((ext_vector_type(8)))  short short8;   // 8 x bf16
typedef __attribute__((ext_vector_type(16))) float f32x16;   // 32x32 MFMA acc
typedef __attribute__((ext_vector_type(4)))  float f4;

// Verified pattern (G4): spread row-bits (byte bits 9-11) into 16B-slot bits.
#define SWZ(byt) ((byt) ^ ((((byt) >> 9) & 7) << 4))

static __device__ __forceinline__ short f2bf(float x) {
    union { float f; unsigned u; } v; v.f = x;
    unsigned r = (v.u + 0x7fffu + ((v.u >> 16) & 1u)) >> 16;
    return (short)r;
}

// ---- kernel 1: normalize basis -> bf16 32x32-fragment-major layout --------
// Bf[(ns*32 + ks)*64 + (n&31) + 32*kg2][8] holds
//   B[n][k = ks*16 + kg2*8 + j]   (ns = n>>5; real n 0..255 -> ns 0..7,
//   imag stored at n+256 -> ns 8..15).
// A wave's (ns,ks) fragment load = 64 lanes x 16 B contiguous = 1 KB.
__global__ __launch_bounds__(256) void prep_kernel(const float* __restrict__ br,
                                                   const float* __restrict__ bi,
                                                   short* __restrict__ Bf) {
    const int lane = threadIdx.x & 63;
    const int wid  = threadIdx.x >> 6;
    const int n    = blockIdx.x * 4 + wid;          // freq 0..255
    const float* pr = br + (size_t)n * WINDOW + lane * 8;
    const float* pi = bi + (size_t)n * WINDOW + lane * 8;
    f4 r0 = *(const f4*)pr;
    f4 r1 = *(const f4*)(pr + 4);
    f4 i0 = *(const f4*)pi;
    f4 i1 = *(const f4*)(pi + 4);
    float ss = 0.f;
#pragma unroll
    for (int j = 0; j < 4; ++j)
        ss += r0[j]*r0[j] + r1[j]*r1[j] + i0[j]*i0[j] + i1[j]*i1[j];
#pragma unroll
    for (int d = 1; d < 64; d <<= 1) ss += __shfl_xor(ss, d, 64);
    const float inv = 1.0f / (sqrtf(ss) + 1e-8f);
    short8 hr, hi;
#pragma unroll
    for (int j = 0; j < 4; ++j) {
        hr[j]     = f2bf(r0[j] * inv);
        hr[j + 4] = f2bf(r1[j] * inv);
        hi[j]     = f2bf(i0[j] * inv);
        hi[j + 4] = f2bf(i1[j] * inv);
    }
    // lane l holds k-range [l*8, l*8+8): ks = l>>1, kg2 = l&1
    const int ks  = lane >> 1, kg2 = lane & 1;
    const int nsR = n >> 5;
    const int nsI = 8 + (n >> 5);
    const int sl  = (n & 31) + 32 * kg2;
    *(short8*)(Bf + ((size_t)(nsR * 32 + ks) * 64 + sl) * 8) = hr;
    *(short8*)(Bf + ((size_t)(nsI * 32 + ks) * 64 + sl) * 8) = hi;
}

// ---- kernel 2: fused norms + bf16 32x32x16 MFMA GEMM -----------------------
// grid = 512 (one block per batch); 1024 thr (16 waves, grid 2m x 8n).
// Block = 128 frames x 512 cols. Wave = 64x64 out via f32x16 acc[2][2]
// (64 AGPR). B from L2 with depth-3 rotating prefetch. ~111 regs -> no spill
// at __launch_bounds__(1024,4).
__global__ __launch_bounds__(1024, 4) void mel_kernel(const float* __restrict__ audio,
                                                      const short* __restrict__ Bf,
                                                      float* __restrict__ out) {
    __shared__ short smp[SAMP_TILE];   // 66048 B, swizzled bf16 samples
    __shared__ float ps[NPS];
    __shared__ float invn[BM];

    const int tid  = threadIdx.x;
    const int lane = tid & 63;
    const int wid  = tid >> 6;          // 0..15

    const int b = blockIdx.x;

    float* out_norms = out;
    float* out_real  = out + 65024;
    float* out_imag  = out + 65024 + 16646144;

    const float* abase = audio + (size_t)b * NSAMP;
    const int smax = NSAMP - 8;

    const int rl32 = lane & 31;
    const int kg2  = lane >> 5;
    const int wm   = wid >> 3;          // 0..1  (m-supers {2wm, 2wm+1})
    const int wn   = wid & 7;           // 0..7  (n-supers {2wn, 2wn+1})

    const short* bp0 = Bf + ((size_t)(2 * wn + 0) * 32 * 64 + lane) * 8;
    const short* bp1 = Bf + ((size_t)(2 * wn + 1) * 32 * 64 + lane) * 8;

    // ---- depth-3 B prefetch (independent of LDS phase) ----
    short8 bb[3][2];
#pragma unroll
    for (int d = 0; d < 3; ++d) {
        bb[d][0] = *(const short8*)(bp0 + (size_t)d * 512);
        bb[d][1] = *(const short8*)(bp1 + (size_t)d * 512);
    }

    // ---- Phase 1: stream 8 samples/thread: f32 -> ss partial + bf16 LDS ----
#pragma unroll
    for (int it = 0; it < 5; ++it) {
        const int sl = it * 8192 + tid * 8;
        float ss = 0.f;
        if (sl < SAMP_TILE) {
            const int slc = sl < smax ? sl : smax;
            f4 v0 = *(const f4*)(abase + slc);
            f4 v1 = *(const f4*)(abase + slc + 4);
            short8 h;
#pragma unroll
            for (int q = 0; q < 4; ++q) {
                ss += v0[q]*v0[q] + v1[q]*v1[q];
                h[q]     = f2bf(v0[q]);
                h[q + 4] = f2bf(v1[q]);
            }
            const int byt = sl * 2;
            *(short8*)((char*)smp + SWZ(byt)) = h;
        }
        ss += __shfl_xor(ss, 1, 64);
        ss += __shfl_xor(ss, 2, 64);
        ss += __shfl_xor(ss, 4, 64);
        ss += __shfl_xor(ss, 8, 64);
        ss += __shfl_xor(ss, 16, 64);
        const int chunk = (it * 8192 + tid * 8) >> 8;
        if ((tid & 31) == 0 && chunk < NPS) ps[chunk] = ss;
    }
    __syncthreads();

    // ---- norms: frame f covers chunks f, f+1 ----
    if (tid < BM) {
        const float nrm = sqrtf(ps[tid] + ps[tid + 1]);
        if (tid < NFRAMES) out_norms[b * NFRAMES + tid] = nrm;
        invn[tid] = 1.0f / (nrm + 1e-8f);
    }

    // ---- Phase 2: K-loop (32 steps of k=16), 32x32x16 MFMA ----
    // A-frag addr: row = msuper*32 + rl32, byt = row*512 + ks*32 + kg2*16.
    // (byt>>9)&7 = (row + (ks>>4)) & 7  -> X0/X1 uniform per lane.
    const int rb0 = ((2 * wm + 0) * 32 + rl32) * 512 + kg2 * 16;
    const int rb1 = ((2 * wm + 1) * 32 + rl32) * 512 + kg2 * 16;
    const int X0  = (rl32 & 7) << 4;
    const int X1  = ((rl32 + 1) & 7) << 4;
    const char* sb = (const char*)smp;

    f32x16 acc[2][2];
    acc[0][0] = (f32x16)0.f; acc[0][1] = (f32x16)0.f;
    acc[1][0] = (f32x16)0.f; acc[1][1] = (f32x16)0.f;

#pragma unroll
    for (int ks = 0; ks < 32; ++ks) {
        const int X  = (ks < 16) ? X0 : X1;
        const int kb = ks * 32;
        short8 a0 = *(const short8*)(sb + ((rb0 + kb) ^ X));
        short8 a1 = *(const short8*)(sb + ((rb1 + kb) ^ X));
        const int cur = ks % 3;
        short8 cb0 = bb[cur][0];
        short8 cb1 = bb[cur][1];
        if (ks < 29) {
            bb[cur][0] = *(const short8*)(bp0 + (size_t)(ks + 3) * 512);
            bb[cur][1] = *(const short8*)(bp1 + (size_t)(ks + 3) * 512);
        }
        acc[0][0] = __builtin_amdgcn_mfma_f32_32x32x16_bf16(a0, cb0, acc[0][0], 0, 0, 0);
        acc[1][0] = __builtin_amdgcn_mfma_f32_32x32x16_bf16(a1, cb0, acc[1][0], 0, 0, 0);
        acc[0][1] = __builtin_amdgcn_mfma_f32_32x32x16_bf16(a0, cb1, acc[0][1], 0, 0, 0);
        acc[1][1] = __builtin_amdgcn_mfma_f32_32x32x16_bf16(a1, cb1, acc[1][1], 0, 0, 0);
    }
    __syncthreads();   // invn visible to all epilogue readers

    // ---- Epilogue: C/D map col=lane&31, row=(reg&3)+8*(reg>>2)+4*(lane>>5) ----
#pragma unroll
    for (int mi = 0; mi < 2; ++mi) {
#pragma unroll
        for (int s = 0; s < 2; ++s) {
            const int n = (2 * wn + s) * 32 + rl32;
            float* dst = (n < NFREQ) ? out_real : out_imag;
            const int kcol = n & (NFREQ - 1);
            const int rbase = (2 * wm + mi) * 32 + 4 * kg2;
#pragma unroll
            for (int r = 0; r < 16; ++r) {
                const int fr = rbase + (r & 3) + 8 * (r >> 2);
                if (fr < NFRAMES)
                    dst[((size_t)b * NFRAMES + fr) * NFREQ + kcol] = acc[mi][s][r] * invn[fr];
            }
        }
    }
}

extern "C" void kernel_launch(void* const* d_in, const int* in_sizes, int n_in,
                              void* d_out, int out_size, void* d_ws, size_t ws_size,
                              hipStream_t stream) {
    const float* audio = (const float*)d_in[0];
    const float* br    = (const float*)d_in[1];
    const float* bi    = (const float*)d_in[2];
    float* out = (float*)d_out;
    short* Bf  = (short*)d_ws;               // 512x512 bf16 = 512 KiB

    prep_kernel<<<64, 256, 0, stream>>>(br, bi, Bf);
    mel_kernel<<<NBATCH, 1024, 0, stream>>>(audio, Bf, out);
}

// Round 11
// 63.161 us; speedup vs baseline: 6.1407x; 1.0172x over previous
//
#include <hip/hip_runtime.h>

#define WINDOW   512
#define STEPSZ   256
#define NFRAMES  127
#define NSAMP    32768
#define NBATCH   512
#define NFREQ    256
#define BM       64
#define SAMP_TILE 16640          // 65 * 256 samples per tile
#define NPS      65

typedef __attribute__((ext_vector_type(8)))  short short8;   // 8 x bf16
typedef __attribute__((ext_vector_type(16))) float f32x16;   // 32x32 MFMA acc
typedef __attribute__((ext_vector_type(4)))  float f4;

// Verified pattern (G4): spread row-bits (byte bits 9-11) into 16B-slot bits.
#define SWZ(byt) ((byt) ^ ((((byt) >> 9) & 7) << 4))

static __device__ __forceinline__ short f2bf(float x) {
    union { float f; unsigned u; } v; v.f = x;
    unsigned r = (v.u + 0x7fffu + ((v.u >> 16) & 1u)) >> 16;
    return (short)r;
}

// ---- kernel 1: normalize basis -> bf16 32x32-fragment-major layout --------
// Bf[(ns*32 + ks)*64 + (n&31) + 32*kg2][8] holds
//   B[n][k = ks*16 + kg2*8 + j]   (ns = n>>5; real n 0..255 -> ns 0..7,
//   imag stored at n+256 -> ns 8..15).
__global__ __launch_bounds__(256) void prep_kernel(const float* __restrict__ br,
                                                   const float* __restrict__ bi,
                                                   short* __restrict__ Bf) {
    const int lane = threadIdx.x & 63;
    const int wid  = threadIdx.x >> 6;
    const int n    = blockIdx.x * 4 + wid;          // freq 0..255
    const float* pr = br + (size_t)n * WINDOW + lane * 8;
    const float* pi = bi + (size_t)n * WINDOW + lane * 8;
    f4 r0 = *(const f4*)pr;
    f4 r1 = *(const f4*)(pr + 4);
    f4 i0 = *(const f4*)pi;
    f4 i1 = *(const f4*)(pi + 4);
    float ss = 0.f;
#pragma unroll
    for (int j = 0; j < 4; ++j)
        ss += r0[j]*r0[j] + r1[j]*r1[j] + i0[j]*i0[j] + i1[j]*i1[j];
#pragma unroll
    for (int d = 1; d < 64; d <<= 1) ss += __shfl_xor(ss, d, 64);
    const float inv = 1.0f / (sqrtf(ss) + 1e-8f);
    short8 hr, hi;
#pragma unroll
    for (int j = 0; j < 4; ++j) {
        hr[j]     = f2bf(r0[j] * inv);
        hr[j + 4] = f2bf(r1[j] * inv);
        hi[j]     = f2bf(i0[j] * inv);
        hi[j + 4] = f2bf(i1[j] * inv);
    }
    const int ks  = lane >> 1, kg2 = lane & 1;
    const int nsR = n >> 5;
    const int nsI = 8 + (n >> 5);
    const int sl  = (n & 31) + 32 * kg2;
    *(short8*)(Bf + ((size_t)(nsR * 32 + ks) * 64 + sl) * 8) = hr;
    *(short8*)(Bf + ((size_t)(nsI * 32 + ks) * 64 + sl) * 8) = hi;
}

// ---- kernel 2: fused norms + bf16 32x32x16 MFMA GEMM -----------------------
// grid = 512 b * 2 m-halves = 1024 blocks; 512 thr (8 waves, 1m x 8n).
// Block = 64 frames x 512 cols; wave = 64m x 64n via f32x16 acc[2][2] (64
// AGPR + ~64 VGPR = 128 unified, same per-wave code as R10). 2 blocks/CU
// resident -> staging/epilogue of one block overlaps the other's K-loop.
__global__ __launch_bounds__(512, 4) void mel_kernel(const float* __restrict__ audio,
                                                     const short* __restrict__ Bf,
                                                     float* __restrict__ out) {
    __shared__ short smp[SAMP_TILE];   // 33280 B, swizzled bf16 samples
    __shared__ float ps[NPS];
    __shared__ float invn[BM];

    const int tid  = threadIdx.x;
    const int lane = tid & 63;
    const int wid  = tid >> 6;          // 0..7 (= wn)

    const int b  = blockIdx.x >> 1;
    const int mh = blockIdx.x & 1;
    const int f0 = mh * BM;

    float* out_norms = out;
    float* out_real  = out + 65024;
    float* out_imag  = out + 65024 + 16646144;

    const float* abase = audio + (size_t)b * NSAMP + f0 * STEPSZ;
    const int smax = NSAMP - f0 * STEPSZ - 8;

    const int rl32 = lane & 31;
    const int kg2  = lane >> 5;
    const int wn   = wid;               // 8 waves, all distinct n (no B dup)

    const short* bp0 = Bf + ((size_t)(2 * wn + 0) * 32 * 64 + lane) * 8;
    const short* bp1 = Bf + ((size_t)(2 * wn + 1) * 32 * 64 + lane) * 8;

    // ---- depth-3 B prefetch (independent of LDS phase) ----
    short8 bb[3][2];
#pragma unroll
    for (int d = 0; d < 3; ++d) {
        bb[d][0] = *(const short8*)(bp0 + (size_t)d * 512);
        bb[d][1] = *(const short8*)(bp1 + (size_t)d * 512);
    }

    // ---- Phase 1: stream 8 samples/thread: f32 -> ss partial + bf16 LDS ----
#pragma unroll
    for (int it = 0; it < 5; ++it) {
        const int sl = it * 4096 + tid * 8;
        float ss = 0.f;
        if (sl < SAMP_TILE) {
            const int slc = sl < smax ? sl : smax;
            f4 v0 = *(const f4*)(abase + slc);
            f4 v1 = *(const f4*)(abase + slc + 4);
            short8 h;
#pragma unroll
            for (int q = 0; q < 4; ++q) {
                ss += v0[q]*v0[q] + v1[q]*v1[q];
                h[q]     = f2bf(v0[q]);
                h[q + 4] = f2bf(v1[q]);
            }
            const int byt = sl * 2;
            *(short8*)((char*)smp + SWZ(byt)) = h;
        }
        ss += __shfl_xor(ss, 1, 64);
        ss += __shfl_xor(ss, 2, 64);
        ss += __shfl_xor(ss, 4, 64);
        ss += __shfl_xor(ss, 8, 64);
        ss += __shfl_xor(ss, 16, 64);
        const int chunk = (it * 4096 + tid * 8) >> 8;
        if ((tid & 31) == 0 && chunk < NPS) ps[chunk] = ss;
    }
    __syncthreads();

    // ---- norms: frame f covers chunks f, f+1 ----
    if (tid < BM) {
        const float nrm = sqrtf(ps[tid] + ps[tid + 1]);
        const int fr = f0 + tid;
        if (fr < NFRAMES) out_norms[b * NFRAMES + fr] = nrm;
        invn[tid] = 1.0f / (nrm + 1e-8f);
    }

    // ---- Phase 2: K-loop (32 steps of k=16), 32x32x16 MFMA ----
    const int rb0 = (0 * 32 + rl32) * 512 + kg2 * 16;
    const int rb1 = (1 * 32 + rl32) * 512 + kg2 * 16;
    const int X0  = (rl32 & 7) << 4;
    const int X1  = ((rl32 + 1) & 7) << 4;
    const char* sb = (const char*)smp;

    f32x16 acc[2][2];
    acc[0][0] = (f32x16)0.f; acc[0][1] = (f32x16)0.f;
    acc[1][0] = (f32x16)0.f; acc[1][1] = (f32x16)0.f;

#pragma unroll
    for (int ks = 0; ks < 32; ++ks) {
        const int X  = (ks < 16) ? X0 : X1;
        const int kb = ks * 32;
        short8 a0 = *(const short8*)(sb + ((rb0 + kb) ^ X));
        short8 a1 = *(const short8*)(sb + ((rb1 + kb) ^ X));
        const int cur = ks % 3;
        short8 cb0 = bb[cur][0];
        short8 cb1 = bb[cur][1];
        if (ks < 29) {
            bb[cur][0] = *(const short8*)(bp0 + (size_t)(ks + 3) * 512);
            bb[cur][1] = *(const short8*)(bp1 + (size_t)(ks + 3) * 512);
        }
        acc[0][0] = __builtin_amdgcn_mfma_f32_32x32x16_bf16(a0, cb0, acc[0][0], 0, 0, 0);
        acc[1][0] = __builtin_amdgcn_mfma_f32_32x32x16_bf16(a1, cb0, acc[1][0], 0, 0, 0);
        acc[0][1] = __builtin_amdgcn_mfma_f32_32x32x16_bf16(a0, cb1, acc[0][1], 0, 0, 0);
        acc[1][1] = __builtin_amdgcn_mfma_f32_32x32x16_bf16(a1, cb1, acc[1][1], 0, 0, 0);
    }
    __syncthreads();   // invn visible to all epilogue readers

    // ---- Epilogue: C/D map col=lane&31, row=(reg&3)+8*(reg>>2)+4*(lane>>5) ----
#pragma unroll
    for (int mi = 0; mi < 2; ++mi) {
#pragma unroll
        for (int s = 0; s < 2; ++s) {
            const int n = (2 * wn + s) * 32 + rl32;
            float* dst = (n < NFREQ) ? out_real : out_imag;
            const int kcol = n & (NFREQ - 1);
            const int rbase = mi * 32 + 4 * kg2;
#pragma unroll
            for (int r = 0; r < 16; ++r) {
                const int rr = rbase + (r & 3) + 8 * (r >> 2);
                const int fr = f0 + rr;
                if (fr < NFRAMES)
                    dst[((size_t)b * NFRAMES + fr) * NFREQ + kcol] = acc[mi][s][r] * invn[rr];
            }
        }
    }
}

extern "C" void kernel_launch(void* const* d_in, const int* in_sizes, int n_in,
                              void* d_out, int out_size, void* d_ws, size_t ws_size,
                              hipStream_t stream) {
    const float* audio = (const float*)d_in[0];
    const float* br    = (const float*)d_in[1];
    const float* bi    = (const float*)d_in[2];
    float* out = (float*)d_out;
    short* Bf  = (short*)d_ws;               // 512x512 bf16 = 512 KiB

    prep_kernel<<<64, 256, 0, stream>>>(br, bi, Bf);
    mel_kernel<<<NBATCH * 2, 512, 0, stream>>>(audio, Bf, out);
}